// Round 1
// baseline (2749.889 us; speedup 1.0000x reference)
//
#include <hip/hip_runtime.h>

#define TB 512   // batch
#define TT 1024  // time
#define TD 64    // input dim
#define TH 128   // hidden
#define TG 384   // 3*H
#define NB 2     // batch rows per block

// 256 blocks x 384 threads (6 waves). Each thread: 4 gate rows x K-quarter.
// Weights held in VGPRs (192 floats/thread = exactly w_hh + w_ih distributed).
__global__ __launch_bounds__(384, 2)
void tinygru_kernel(const float* __restrict__ x,
                    const float* __restrict__ mask,
                    const float* __restrict__ w_ih,
                    const float* __restrict__ w_hh,
                    const float* __restrict__ b_ih,
                    const float* __restrict__ b_hh,
                    const float* __restrict__ Wo,
                    const float* __restrict__ bo,
                    float* __restrict__ out)
{
    __shared__ float h_lds[NB][TH];
    __shared__ float xb[NB][TD];
    __shared__ float px[NB][TG * 5];   // stride 5: kills the x4 bank stride
    __shared__ float ph[NB][TG * 5];
    __shared__ float bih[TG], bhh[TG];
    __shared__ float wo_l[2][TH];
    __shared__ float bo_l[2];

    const int tid = threadIdx.x;
    const int b0 = blockIdx.x * NB;
    const int q  = tid & 3;        // K-quarter: k in [q*32, q*32+32) for w_hh
    const int gq = tid >> 2;       // gate-row group [0,96)
    const int gbase = gq * 4;      // 4 consecutive gate rows

    // ---- one-time: weights -> registers ----
    float4 wh4[4][8];   // [row][k4] : w_hh[gbase+row][q*32 + 4*k4 ..]
    float4 wi4[4][4];   // [row][k4] : w_ih[gbase+row][q*16 + 4*k4 ..]
    #pragma unroll
    for (int rr = 0; rr < 4; ++rr) {
        const float4* p = (const float4*)(w_hh + (size_t)(gbase + rr) * TH + q * 32);
        #pragma unroll
        for (int k = 0; k < 8; ++k) wh4[rr][k] = p[k];
        const float4* p2 = (const float4*)(w_ih + (size_t)(gbase + rr) * TD + q * 16);
        #pragma unroll
        for (int k = 0; k < 4; ++k) wi4[rr][k] = p2[k];
    }

    if (tid < TG) { bih[tid] = b_ih[tid]; bhh[tid] = b_hh[tid]; }
    if (tid < 2 * TH) wo_l[tid >> 7][tid & 127] = Wo[tid];
    if (tid < 2) bo_l[tid] = bo[tid];
    if (tid < NB * TH) h_lds[tid >> 7][tid & 127] = 0.0f;
    __syncthreads();

    for (int t = 0; t < TT; ++t) {
        // ---- stage A: load x_t for both rows (coalesced) ----
        if (tid < NB * TD) {
            int b = tid >> 6, k = tid & 63;
            xb[b][k] = x[((size_t)(b0 + b) * TT + t) * TD + k];
        }
        __syncthreads();   // xb ready; h from prev step ready

        // ---- stage B: partial matvecs (weights in regs, h/x broadcast) ----
        {
            float ah[4][2] = {{0.f,0.f},{0.f,0.f},{0.f,0.f},{0.f,0.f}};
            float ax[4][2] = {{0.f,0.f},{0.f,0.f},{0.f,0.f},{0.f,0.f}};
            const float4* h0 = (const float4*)&h_lds[0][q * 32];
            const float4* h1 = (const float4*)&h_lds[1][q * 32];
            #pragma unroll
            for (int k = 0; k < 8; ++k) {
                float4 a = h0[k], c = h1[k];
                #pragma unroll
                for (int rr = 0; rr < 4; ++rr) {
                    float4 w = wh4[rr][k];
                    ah[rr][0] += w.x*a.x + w.y*a.y + w.z*a.z + w.w*a.w;
                    ah[rr][1] += w.x*c.x + w.y*c.y + w.z*c.z + w.w*c.w;
                }
            }
            const float4* x0 = (const float4*)&xb[0][q * 16];
            const float4* x1 = (const float4*)&xb[1][q * 16];
            #pragma unroll
            for (int k = 0; k < 4; ++k) {
                float4 a = x0[k], c = x1[k];
                #pragma unroll
                for (int rr = 0; rr < 4; ++rr) {
                    float4 w = wi4[rr][k];
                    ax[rr][0] += w.x*a.x + w.y*a.y + w.z*a.z + w.w*a.w;
                    ax[rr][1] += w.x*c.x + w.y*c.y + w.z*c.z + w.w*c.w;
                }
            }
            #pragma unroll
            for (int rr = 0; rr < 4; ++rr) {
                int gi = (gbase + rr) * 5 + q;
                ph[0][gi] = ah[rr][0];
                ph[1][gi] = ah[rr][1];
                px[0][gi] = ax[rr][0];
                px[1][gi] = ax[rr][1];
            }
        }
        __syncthreads();   // partials ready

        // ---- stage C: reduce partials, gates, h update (4 waves) ----
        if (tid < NB * TH) {
            int b = tid >> 7, j = tid & 127;
            float xr = bih[j],       hr = bhh[j];
            float xz = bih[128 + j], hz = bhh[128 + j];
            float xn = bih[256 + j], hn = bhh[256 + j];
            #pragma unroll
            for (int qq = 0; qq < 4; ++qq) {
                xr += px[b][j * 5 + qq];          hr += ph[b][j * 5 + qq];
                xz += px[b][(128 + j) * 5 + qq];  hz += ph[b][(128 + j) * 5 + qq];
                xn += px[b][(256 + j) * 5 + qq];  hn += ph[b][(256 + j) * 5 + qq];
            }
            float r = 1.0f / (1.0f + __expf(-(xr + hr)));
            float z = 1.0f / (1.0f + __expf(-(xz + hz)));
            float pre_n = xn + r * hn;               // n-gate: xg and hg kept separate
            float e2 = __expf(2.0f * pre_n);
            float n = 1.0f - 2.0f / (e2 + 1.0f);     // tanh; saturates correctly at +/-inf
            float hold = h_lds[b][j];
            float hnew = (1.0f - z) * n + z * hold;
            float m = mask[(size_t)(b0 + b) * TT + t];
            h_lds[b][j] = m * hnew + (1.0f - m) * hold;
        }
        __syncthreads();   // h ready

        // ---- stage D: logits = h @ Wo^T + bo (4 waves, shuffle reduce) ----
        if (tid < 256) {
            int wv = tid >> 6, lane = tid & 63;
            int b = wv >> 1, o = wv & 1;
            float v = h_lds[b][lane] * wo_l[o][lane]
                    + h_lds[b][64 + lane] * wo_l[o][64 + lane];
            #pragma unroll
            for (int off = 32; off > 0; off >>= 1)
                v += __shfl_xor(v, off);
            if (lane == 0)
                out[((size_t)(b0 + b) * TT + t) * 2 + o] = v + bo_l[o];
        }
        // no sync needed here: stage D only reads h; next writer of h (stage C)
        // is fenced behind two syncthreads that stage-D threads participate in.
    }
}

extern "C" void kernel_launch(void* const* d_in, const int* in_sizes, int n_in,
                              void* d_out, int out_size, void* d_ws, size_t ws_size,
                              hipStream_t stream) {
    const float* x    = (const float*)d_in[0];
    const float* mask = (const float*)d_in[1];
    const float* w_ih = (const float*)d_in[2];
    const float* w_hh = (const float*)d_in[3];
    const float* b_ih = (const float*)d_in[4];
    const float* b_hh = (const float*)d_in[5];
    const float* Wo   = (const float*)d_in[6];
    const float* bo   = (const float*)d_in[7];
    float* out = (float*)d_out;
    (void)in_sizes; (void)n_in; (void)out_size; (void)d_ws; (void)ws_size;

    tinygru_kernel<<<TB / NB, 384, 0, stream>>>(x, mask, w_ih, w_hh, b_ih, b_hh, Wo, bo, out);
}

// Round 2
// 2103.381 us; speedup vs baseline: 1.3074x; 1.3074x over previous
//
#include <hip/hip_runtime.h>

#define TB 512   // batch
#define TT 1024  // time
#define TD 64    // input dim
#define TH 128   // hidden

typedef __attribute__((ext_vector_type(8))) short short8;  // 8 bf16 (4 VGPRs)
typedef __attribute__((ext_vector_type(4))) float f32x4;   // MFMA C/D

// fp32 -> bf16 bits, round-to-nearest-even
__device__ __forceinline__ short bfb(float f) {
    unsigned u = __builtin_bit_cast(unsigned, f);
    u = (u + 0x7FFFu + ((u >> 16) & 1u)) >> 16;
    return (short)u;
}
__device__ __forceinline__ float sigm(float v) {
    return 1.0f / (1.0f + __expf(-v));
}
__device__ __forceinline__ float tanh_fast(float v) {
    float e = __expf(2.0f * v);     // +inf -> 1, 0 -> -1 : saturates correctly
    return 1.0f - 2.0f / (e + 1.0f);
}

// 32 blocks x 512 threads (8 waves). Block owns batch tile of 16 (MFMA M),
// wave w owns gate columns {16w+c, 128+16w+c, 256+16w+c} -> r/z/n accs for one
// (batch,hidden) pair are lane-local; gate math entirely in registers.
__global__ __launch_bounds__(512, 2)
void gru_mfma(const float* __restrict__ x, const float* __restrict__ mask,
              const float* __restrict__ w_ih, const float* __restrict__ w_hh,
              const float* __restrict__ b_ih, const float* __restrict__ b_hh,
              const float* __restrict__ Wo, const float* __restrict__ bo,
              float* __restrict__ out)
{
    __shared__ short hbuf[2][16][136];   // h(t) bf16, A-frag layout, +8 pad
    __shared__ float mlds[TT][16];       // full mask tile for this batch slice (64KB)

    const int tid  = threadIdx.x;
    const int w    = tid >> 6;          // wave 0..7
    const int lane = tid & 63;
    const int c    = lane & 15;         // MFMA n/m fast index
    const int quad = lane >> 4;         // MFMA k-chunk / row-group
    const int Bb   = blockIdx.x * 16;   // batch base

    // ---- one-time: stage entire mask slice (16 rows x 1024 t) ----
    for (int i = tid; i < TT * 16; i += 512) {
        int t = i >> 4, b = i & 15;
        mlds[t][b] = mask[(size_t)(Bb + b) * TT + t];
    }
    for (int i = tid; i < 2 * 16 * 136; i += 512) (&hbuf[0][0][0])[i] = 0;

    const int jr = 16 * w + c;          // hidden unit this lane owns
    const int jz = TH + jr;
    const int jn = 2 * TH + jr;

    // ---- one-time: weights -> bf16 B-fragments in registers ----
    // B-frag layout: lane holds B[k = 32*kt + quad*8 + j][n = gate col = base + c]
    short8 whh[3][4], wih[3][2], wof[4];
    {
        const int gg[3] = {jr, jz, jn};
        #pragma unroll
        for (int g = 0; g < 3; ++g) {
            #pragma unroll
            for (int kt = 0; kt < 4; ++kt) {
                const float* p = w_hh + (size_t)gg[g] * TH + 32 * kt + 8 * quad;
                short8 f;
                #pragma unroll
                for (int j = 0; j < 8; ++j) f[j] = bfb(p[j]);
                whh[g][kt] = f;
            }
            #pragma unroll
            for (int kt = 0; kt < 2; ++kt) {
                const float* p = w_ih + (size_t)gg[g] * TD + 32 * kt + 8 * quad;
                short8 f;
                #pragma unroll
                for (int j = 0; j < 8; ++j) f[j] = bfb(p[j]);
                wih[g][kt] = f;
            }
        }
        #pragma unroll
        for (int kt = 0; kt < 4; ++kt) {
            short8 f = {0,0,0,0,0,0,0,0};    // cols >=2 multiply by zero
            if (c < 2) {
                const float* p = Wo + (size_t)c * TH + 32 * kt + 8 * quad;
                #pragma unroll
                for (int j = 0; j < 8; ++j) f[j] = bfb(p[j]);
            }
            wof[kt] = f;
        }
    }

    const float bsr = b_ih[jr] + b_hh[jr];
    const float bsz = b_ih[jz] + b_hh[jz];
    const float bin = b_ih[jn];           // n-gate: keep x/h biases separate
    const float bhn = b_hh[jn];
    const float boc = (c < 2) ? bo[c] : 0.0f;

    // A-frag for x: lane needs x[Bb+c][t][32*kt + 8*quad + j]
    const float* xrow = x + (size_t)(Bb + c) * TT * TD + 8 * quad;

    short8 xf[2];
    #pragma unroll
    for (int kt = 0; kt < 2; ++kt) {        // x(0)
        f32x4 a = *(const f32x4*)(xrow + 32 * kt);
        f32x4 b = *(const f32x4*)(xrow + 32 * kt + 4);
        short8 f;
        #pragma unroll
        for (int j = 0; j < 4; ++j) { f[j] = bfb(a[j]); f[4 + j] = bfb(b[j]); }
        xf[kt] = f;
    }

    f32x4 hold = {0.f, 0.f, 0.f, 0.f};      // fp32 h for rows quad*4+i, unit jr

    for (int t = 0; t < TT; ++t) {
        __syncthreads();                    // the ONE barrier per step
        const int rb = t & 1, wb = rb ^ 1;

        // A-frags of h(t-1): lane holds h[m=c][k=quad*8+j] per k-tile
        short8 ha[4];
        #pragma unroll
        for (int kt = 0; kt < 4; ++kt)
            ha[kt] = *(const short8*)(&hbuf[rb][c][32 * kt + 8 * quad]);

        // prefetch x(t+1) (independent of h -> hides global latency)
        f32x4 nxa0, nxb0, nxa1, nxb1;
        if (t + 1 < TT) {
            const float* p = xrow + (size_t)(t + 1) * TD;
            nxa0 = *(const f32x4*)(p);
            nxb0 = *(const f32x4*)(p + 4);
            nxa1 = *(const f32x4*)(p + 32);
            nxb1 = *(const f32x4*)(p + 36);
        }

        // logits for step t-1 from the same h(t-1) frags (wave 0 only)
        if (w == 0 && t > 0) {
            f32x4 lacc = {0.f, 0.f, 0.f, 0.f};
            #pragma unroll
            for (int kt = 0; kt < 4; ++kt)
                lacc = __builtin_amdgcn_mfma_f32_16x16x32_bf16(ha[kt], wof[kt], lacc, 0, 0, 0);
            if (c < 2) {
                #pragma unroll
                for (int i = 0; i < 4; ++i)
                    out[((size_t)(Bb + 4 * quad + i) * TT + (t - 1)) * 2 + c] = lacc[i] + boc;
            }
        }

        // recurrent + input-projection MFMAs (4 independent acc chains)
        f32x4 ar  = {0.f,0.f,0.f,0.f};
        f32x4 az  = {0.f,0.f,0.f,0.f};
        f32x4 anh = {0.f,0.f,0.f,0.f};
        f32x4 anx = {0.f,0.f,0.f,0.f};
        #pragma unroll
        for (int kt = 0; kt < 4; ++kt) {
            ar  = __builtin_amdgcn_mfma_f32_16x16x32_bf16(ha[kt], whh[0][kt], ar , 0, 0, 0);
            az  = __builtin_amdgcn_mfma_f32_16x16x32_bf16(ha[kt], whh[1][kt], az , 0, 0, 0);
            anh = __builtin_amdgcn_mfma_f32_16x16x32_bf16(ha[kt], whh[2][kt], anh, 0, 0, 0);
        }
        #pragma unroll
        for (int kt = 0; kt < 2; ++kt) {
            ar  = __builtin_amdgcn_mfma_f32_16x16x32_bf16(xf[kt], wih[0][kt], ar , 0, 0, 0);
            az  = __builtin_amdgcn_mfma_f32_16x16x32_bf16(xf[kt], wih[1][kt], az , 0, 0, 0);
            anx = __builtin_amdgcn_mfma_f32_16x16x32_bf16(xf[kt], wih[2][kt], anx, 0, 0, 0);
        }

        // gate epilogue, fully lane-local (C/D: row=quad*4+i, col=c)
        f32x4 mrow = *(const f32x4*)(&mlds[t][4 * quad]);
        #pragma unroll
        for (int i = 0; i < 4; ++i) {
            float r  = sigm(ar[i] + bsr);
            float z  = sigm(az[i] + bsz);
            float n  = tanh_fast((anx[i] + bin) + r * (anh[i] + bhn));
            float hn = n + z * (hold[i] - n);                 // (1-z)n + z*h
            float hv = hold[i] + mrow[i] * (hn - hold[i]);    // mask blend
            hold[i] = hv;                                     // fp32 state stays in regs
            hbuf[wb][4 * quad + i][jr] = bfb(hv);             // bf16 copy for next A-frag
        }

        // convert prefetched x(t+1) after MFMAs (load latency already covered)
        if (t + 1 < TT) {
            short8 f;
            #pragma unroll
            for (int j = 0; j < 4; ++j) { f[j] = bfb(nxa0[j]); f[4 + j] = bfb(nxb0[j]); }
            xf[0] = f;
            #pragma unroll
            for (int j = 0; j < 4; ++j) { f[j] = bfb(nxa1[j]); f[4 + j] = bfb(nxb1[j]); }
            xf[1] = f;
        }
    }

    // flush logits for t = TT-1 (h(TT-1) sits in hbuf[0])
    __syncthreads();
    if (w == 0) {
        short8 ha[4];
        #pragma unroll
        for (int kt = 0; kt < 4; ++kt)
            ha[kt] = *(const short8*)(&hbuf[0][c][32 * kt + 8 * quad]);
        f32x4 lacc = {0.f, 0.f, 0.f, 0.f};
        #pragma unroll
        for (int kt = 0; kt < 4; ++kt)
            lacc = __builtin_amdgcn_mfma_f32_16x16x32_bf16(ha[kt], wof[kt], lacc, 0, 0, 0);
        if (c < 2) {
            #pragma unroll
            for (int i = 0; i < 4; ++i)
                out[((size_t)(Bb + 4 * quad + i) * TT + (TT - 1)) * 2 + c] = lacc[i] + boc;
        }
    }
}

extern "C" void kernel_launch(void* const* d_in, const int* in_sizes, int n_in,
                              void* d_out, int out_size, void* d_ws, size_t ws_size,
                              hipStream_t stream) {
    const float* x    = (const float*)d_in[0];
    const float* mask = (const float*)d_in[1];
    const float* w_ih = (const float*)d_in[2];
    const float* w_hh = (const float*)d_in[3];
    const float* b_ih = (const float*)d_in[4];
    const float* b_hh = (const float*)d_in[5];
    const float* Wo   = (const float*)d_in[6];
    const float* bo   = (const float*)d_in[7];
    float* out = (float*)d_out;
    (void)in_sizes; (void)n_in; (void)out_size; (void)d_ws; (void)ws_size;

    gru_mfma<<<TB / 16, 512, 0, stream>>>(x, mask, w_ih, w_hh, b_ih, b_hh, Wo, bo, out);
}

// Round 3
// 1396.242 us; speedup vs baseline: 1.9695x; 1.5065x over previous
//
#include <hip/hip_runtime.h>

#define TB 512   // batch
#define TT 1024  // time
#define TD 64    // input dim
#define TH 128   // hidden

typedef __attribute__((ext_vector_type(8))) short short8;  // 8 bf16 (4 VGPRs)
typedef __attribute__((ext_vector_type(4))) float f32x4;   // MFMA C/D

// fp32 -> bf16 bits, round-to-nearest-even
__device__ __forceinline__ short bfb(float f) {
    unsigned u = __builtin_bit_cast(unsigned, f);
    u = (u + 0x7FFFu + ((u >> 16) & 1u)) >> 16;
    return (short)u;
}
__device__ __forceinline__ float sigm(float v) {
    return 1.0f / (1.0f + __expf(-v));
}
__device__ __forceinline__ float tanh_fast(float v) {
    float e = __expf(2.0f * v);     // +inf -> 1, 0 -> -1 : saturates correctly
    return 1.0f - 2.0f / (e + 1.0f);
}

// Barrier with LDS-only drain: h handoff through LDS needs lgkmcnt(0), but
// global x-prefetch loads / logit stores stay IN FLIGHT across the barrier
// (vs __syncthreads' vmcnt(0) drain which serialized them into every step).
#define BAR() asm volatile("s_waitcnt lgkmcnt(0)\n\ts_barrier" ::: "memory")

// ---------------- phase 1: x -> bf16 A-fragment order in workspace ----------
// ws layout (short8 units): [bb 0..31][t][kt 0..1][lane 0..63]
// lane holds x[Bb + (lane&15)][t][32*kt + 8*(lane>>4) + j], j=0..7
__global__ __launch_bounds__(256)
void xswz(const float* __restrict__ x, short8* __restrict__ ws) {
    int gid  = blockIdx.x * 256 + threadIdx.x;     // 32*1024*2*64 = 4.19M
    int lane = gid & 63;
    int kt   = (gid >> 6) & 1;
    int t    = (gid >> 7) & (TT - 1);
    int bb   = gid >> 17;
    int c = lane & 15, quad = lane >> 4;
    const float* p = x + ((size_t)(bb * 16 + c) * TT + t) * TD + 32 * kt + 8 * quad;
    f32x4 a = *(const f32x4*)p;
    f32x4 b = *(const f32x4*)(p + 4);
    short8 f;
    #pragma unroll
    for (int j = 0; j < 4; ++j) { f[j] = bfb(a[j]); f[4 + j] = bfb(b[j]); }
    ws[gid] = f;                                   // fully coalesced 16B/lane
}

// ---------------- phase 2: the scan -----------------------------------------
// 32 blocks x 512 threads (8 waves). Block owns batch tile of 16 (MFMA M),
// wave w owns gate columns {16w+c, 128+16w+c, 256+16w+c} -> r/z/n accs for one
// (batch,hidden) pair are lane-local; gate math entirely in registers.
template <bool USE_WS>
__global__ __launch_bounds__(512, 2)
void gru_mfma(const float* __restrict__ x, const short8* __restrict__ xw,
              const float* __restrict__ mask,
              const float* __restrict__ w_ih, const float* __restrict__ w_hh,
              const float* __restrict__ b_ih, const float* __restrict__ b_hh,
              const float* __restrict__ Wo, const float* __restrict__ bo,
              float* __restrict__ out)
{
    __shared__ short hbuf[2][16][136];   // h(t) bf16, A-frag layout, +8 pad
    __shared__ float mlds[TT][16];       // mask tile for this batch slice (64KB)

    const int tid  = threadIdx.x;
    const int w    = tid >> 6;          // wave 0..7
    const int lane = tid & 63;
    const int c    = lane & 15;         // MFMA n/m fast index
    const int quad = lane >> 4;         // MFMA k-chunk / row-group
    const int Bb   = blockIdx.x * 16;   // batch base

    // ---- one-time: stage mask slice + zero h ----
    for (int i = tid; i < TT * 16; i += 512) {
        int t = i >> 4, b = i & 15;
        mlds[t][b] = mask[(size_t)(Bb + b) * TT + t];
    }
    for (int i = tid; i < 2 * 16 * 136; i += 512) (&hbuf[0][0][0])[i] = 0;

    const int jr = 16 * w + c;          // hidden unit this lane owns
    const int jz = TH + jr;
    const int jn = 2 * TH + jr;

    // ---- one-time: weights -> bf16 B-fragments in registers ----
    short8 whh[3][4], wih[3][2], wof[4];
    {
        const int gg[3] = {jr, jz, jn};
        #pragma unroll
        for (int g = 0; g < 3; ++g) {
            #pragma unroll
            for (int kt = 0; kt < 4; ++kt) {
                const float* p = w_hh + (size_t)gg[g] * TH + 32 * kt + 8 * quad;
                short8 f;
                #pragma unroll
                for (int j = 0; j < 8; ++j) f[j] = bfb(p[j]);
                whh[g][kt] = f;
            }
            #pragma unroll
            for (int kt = 0; kt < 2; ++kt) {
                const float* p = w_ih + (size_t)gg[g] * TD + 32 * kt + 8 * quad;
                short8 f;
                #pragma unroll
                for (int j = 0; j < 8; ++j) f[j] = bfb(p[j]);
                wih[g][kt] = f;
            }
        }
        #pragma unroll
        for (int kt = 0; kt < 4; ++kt) {
            short8 f = {0,0,0,0,0,0,0,0};    // cols >=2 multiply by zero
            if (c < 2) {
                const float* p = Wo + (size_t)c * TH + 32 * kt + 8 * quad;
                #pragma unroll
                for (int j = 0; j < 8; ++j) f[j] = bfb(p[j]);
            }
            wof[kt] = f;
        }
    }

    const float bsr = b_ih[jr] + b_hh[jr];
    const float bsz = b_ih[jz] + b_hh[jz];
    const float bin = b_ih[jn];           // n-gate: keep x/h biases separate
    const float bhn = b_hh[jn];
    const float boc = (c < 2) ? bo[c] : 0.0f;

    // x access bases
    const short8* xwb  = xw + (size_t)blockIdx.x * TT * 128 + lane;      // USE_WS
    const float*  xrow = x + (size_t)(Bb + c) * TT * TD + 8 * quad;      // fallback

    // double-buffered x A-fragments (static reg indexing via 2x unrolled loop)
    short8 xf0[2], xf1[2];
    if (USE_WS) {
        xf0[0] = xwb[0];
        xf0[1] = xwb[64];
    } else {
        #pragma unroll
        for (int kt = 0; kt < 2; ++kt) {
            f32x4 a = *(const f32x4*)(xrow + 32 * kt);
            f32x4 b = *(const f32x4*)(xrow + 32 * kt + 4);
            short8 f;
            #pragma unroll
            for (int j = 0; j < 4; ++j) { f[j] = bfb(a[j]); f[4 + j] = bfb(b[j]); }
            xf0[kt] = f;
        }
    }

    f32x4 hold = {0.f, 0.f, 0.f, 0.f};      // fp32 h for rows quad*4+i, unit jr

#define STEP(T, XC, XN)                                                         \
  {                                                                             \
    const int t = (T);                                                          \
    BAR();                                                                      \
    const int rb = t & 1, wb = rb ^ 1;                                          \
    short8 ha[4];                                                               \
    _Pragma("unroll")                                                           \
    for (int kt = 0; kt < 4; ++kt)                                              \
        ha[kt] = *(const short8*)(&hbuf[rb][c][32 * kt + 8 * quad]);            \
    /* prefetch x(t+1); stays in flight across the next barrier */              \
    const int tn = (t + 1 < TT) ? t + 1 : TT - 1;                               \
    f32x4 nxa0, nxb0, nxa1, nxb1;                                               \
    if (USE_WS) {                                                               \
        XN[0] = xwb[(size_t)tn * 128];                                          \
        XN[1] = xwb[(size_t)tn * 128 + 64];                                     \
    } else {                                                                    \
        const float* p = xrow + (size_t)tn * TD;                                \
        nxa0 = *(const f32x4*)(p);      nxb0 = *(const f32x4*)(p + 4);          \
        nxa1 = *(const f32x4*)(p + 32); nxb1 = *(const f32x4*)(p + 36);         \
    }                                                                           \
    /* recurrent + input-projection MFMAs (4 independent acc chains) */         \
    f32x4 ar = {0.f,0.f,0.f,0.f}, az = {0.f,0.f,0.f,0.f};                       \
    f32x4 anh = {0.f,0.f,0.f,0.f}, anx = {0.f,0.f,0.f,0.f};                     \
    _Pragma("unroll")                                                           \
    for (int kt = 0; kt < 4; ++kt) {                                            \
        ar  = __builtin_amdgcn_mfma_f32_16x16x32_bf16(ha[kt], whh[0][kt], ar , 0,0,0); \
        az  = __builtin_amdgcn_mfma_f32_16x16x32_bf16(ha[kt], whh[1][kt], az , 0,0,0); \
        anh = __builtin_amdgcn_mfma_f32_16x16x32_bf16(ha[kt], whh[2][kt], anh, 0,0,0); \
    }                                                                           \
    _Pragma("unroll")                                                           \
    for (int kt = 0; kt < 2; ++kt) {                                            \
        ar  = __builtin_amdgcn_mfma_f32_16x16x32_bf16(XC[kt], wih[0][kt], ar , 0,0,0); \
        az  = __builtin_amdgcn_mfma_f32_16x16x32_bf16(XC[kt], wih[1][kt], az , 0,0,0); \
        anx = __builtin_amdgcn_mfma_f32_16x16x32_bf16(XC[kt], wih[2][kt], anx, 0,0,0); \
    }                                                                           \
    /* logits for step t-1 from the same h(t-1) frags (wave 0 only) */          \
    if (w == 0 && t > 0) {                                                      \
        f32x4 lacc = {0.f, 0.f, 0.f, 0.f};                                      \
        _Pragma("unroll")                                                       \
        for (int kt = 0; kt < 4; ++kt)                                          \
            lacc = __builtin_amdgcn_mfma_f32_16x16x32_bf16(ha[kt], wof[kt], lacc, 0,0,0); \
        if (c < 2) {                                                            \
            _Pragma("unroll")                                                   \
            for (int i = 0; i < 4; ++i)                                         \
                out[((size_t)(Bb + 4 * quad + i) * TT + (t - 1)) * 2 + c] = lacc[i] + boc; \
        }                                                                       \
    }                                                                           \
    /* gate epilogue, fully lane-local (C/D: row=quad*4+i, col=c) */            \
    f32x4 mrow = *(const f32x4*)(&mlds[t][4 * quad]);                           \
    _Pragma("unroll")                                                           \
    for (int i = 0; i < 4; ++i) {                                               \
        float r  = sigm(ar[i] + bsr);                                           \
        float z  = sigm(az[i] + bsz);                                           \
        float n  = tanh_fast((anx[i] + bin) + r * (anh[i] + bhn));              \
        float hn = n + z * (hold[i] - n);                                       \
        float hv = hold[i] + mrow[i] * (hn - hold[i]);                          \
        hold[i] = hv;                                                           \
        hbuf[wb][4 * quad + i][jr] = bfb(hv);                                   \
    }                                                                           \
    if (!USE_WS) {                                                              \
        short8 f;                                                               \
        _Pragma("unroll")                                                       \
        for (int j = 0; j < 4; ++j) { f[j] = bfb(nxa0[j]); f[4+j] = bfb(nxb0[j]); } \
        XN[0] = f;                                                              \
        _Pragma("unroll")                                                       \
        for (int j = 0; j < 4; ++j) { f[j] = bfb(nxa1[j]); f[4+j] = bfb(nxb1[j]); } \
        XN[1] = f;                                                              \
    }                                                                           \
  }

    for (int t2 = 0; t2 < TT; t2 += 2) {
        STEP(t2,     xf0, xf1);
        STEP(t2 + 1, xf1, xf0);
    }
#undef STEP

    // flush logits for t = TT-1 (h(TT-1) sits in hbuf[0])
    BAR();
    if (w == 0) {
        short8 ha[4];
        #pragma unroll
        for (int kt = 0; kt < 4; ++kt)
            ha[kt] = *(const short8*)(&hbuf[0][c][32 * kt + 8 * quad]);
        f32x4 lacc = {0.f, 0.f, 0.f, 0.f};
        #pragma unroll
        for (int kt = 0; kt < 4; ++kt)
            lacc = __builtin_amdgcn_mfma_f32_16x16x32_bf16(ha[kt], wof[kt], lacc, 0, 0, 0);
        if (c < 2) {
            #pragma unroll
            for (int i = 0; i < 4; ++i)
                out[((size_t)(Bb + 4 * quad + i) * TT + (TT - 1)) * 2 + c] = lacc[i] + boc;
        }
    }
}

extern "C" void kernel_launch(void* const* d_in, const int* in_sizes, int n_in,
                              void* d_out, int out_size, void* d_ws, size_t ws_size,
                              hipStream_t stream) {
    const float* x    = (const float*)d_in[0];
    const float* mask = (const float*)d_in[1];
    const float* w_ih = (const float*)d_in[2];
    const float* w_hh = (const float*)d_in[3];
    const float* b_ih = (const float*)d_in[4];
    const float* b_hh = (const float*)d_in[5];
    const float* Wo   = (const float*)d_in[6];
    const float* bo   = (const float*)d_in[7];
    float* out = (float*)d_out;
    (void)in_sizes; (void)n_in; (void)out_size;

    const size_t need = (size_t)32 * TT * 2 * 64 * sizeof(short8);  // 67.1 MB
    if (ws_size >= need) {
        short8* xw = (short8*)d_ws;
        xswz<<<(32 * TT * 2 * 64) / 256, 256, 0, stream>>>(x, xw);
        gru_mfma<true><<<TB / 16, 512, 0, stream>>>(x, xw, mask, w_ih, w_hh,
                                                    b_ih, b_hh, Wo, bo, out);
    } else {
        gru_mfma<false><<<TB / 16, 512, 0, stream>>>(x, (const short8*)nullptr, mask,
                                                     w_ih, w_hh, b_ih, b_hh, Wo, bo, out);
    }
}

// Round 4
// 1077.170 us; speedup vs baseline: 2.5529x; 1.2962x over previous
//
#include <hip/hip_runtime.h>

#define TB 512   // batch
#define TT 1024  // time
#define TD 64    // input dim
#define TH 128   // hidden
#define NR 8     // batch rows per block -> 64 blocks / 64 CUs

typedef __attribute__((ext_vector_type(8))) short short8;  // 8 bf16 (4 VGPRs)
typedef __attribute__((ext_vector_type(4))) float f32x4;   // MFMA C/D

#define LOG2E 1.44269504f

// fp32 -> bf16 bits, round-to-nearest-even
__device__ __forceinline__ short bfb(float f) {
    unsigned u = __builtin_bit_cast(unsigned, f);
    u = (u + 0x7FFFu + ((u >> 16) & 1u)) >> 16;
    return (short)u;
}

// gate epilogue for one (batch-row, hidden-unit) pair; raw v_exp/v_rcp only
__device__ __forceinline__ float gate_update(float ar, float az, float anx, float anh,
                                             float crK, float czK, float bin, float bhn,
                                             float m, float h) {
    float er = __builtin_amdgcn_exp2f(__builtin_fmaf(ar, -LOG2E, crK));
    float r  = __builtin_amdgcn_rcpf(1.0f + er);
    float ez = __builtin_amdgcn_exp2f(__builtin_fmaf(az, -LOG2E, czK));
    float z  = __builtin_amdgcn_rcpf(1.0f + ez);
    float p  = (anx + bin) + r * (anh + bhn);
    float e2 = __builtin_amdgcn_exp2f(p * (2.0f * LOG2E));
    float n  = __builtin_fmaf(-2.0f, __builtin_amdgcn_rcpf(1.0f + e2), 1.0f);  // tanh
    float hn = n + z * (h - n);
    return h + m * (hn - h);
}

// Barrier with LDS-only drain: global loads/stores stay in flight across it.
#define BAR() asm volatile("s_waitcnt lgkmcnt(0)\n\ts_barrier" ::: "memory")

// ---------------- phase 1: x -> bf16 A-fragment order (compact, 8 rows) -----
// ws layout (short8 units): [blk 0..63][t][kt 0..1][e 0..31], e = c*4 + quad
// holds x[blk*8 + c][t][32*kt + 8*quad + j], j=0..7
__global__ __launch_bounds__(256)
void xswz(const float* __restrict__ x, short8* __restrict__ ws) {
    int gid = blockIdx.x * 256 + threadIdx.x;       // 64*1024*2*32 = 4.19M
    int e   = gid & 31;
    int kt  = (gid >> 5) & 1;
    int t   = (gid >> 6) & (TT - 1);
    int blk = gid >> 16;
    int c = e >> 2, quad = e & 3;
    const float* p = x + ((size_t)(blk * NR + c) * TT + t) * TD + 32 * kt + 8 * quad;
    f32x4 a = *(const f32x4*)p;
    f32x4 b = *(const f32x4*)(p + 4);
    short8 f;
    #pragma unroll
    for (int j = 0; j < 4; ++j) { f[j] = bfb(a[j]); f[4 + j] = bfb(b[j]); }
    ws[gid] = f;
}

// ---------------- phase 2: the scan -----------------------------------------
// 64 blocks x 512 threads. Block owns 8 batch rows (MFMA rows 8..15 are zero).
// Phase A (per wave w): MFMA for gate cols {16w+c, +128, +256}; real C/D rows
// (quad<2) go to exch[]. Phase B: all 512 lanes grab 2 (row,col) pairs
// (rr=tid&3 / rr+4, jj=tid>>2), run the gate math, write h to hbuf.
template <bool USE_WS>
__global__ __launch_bounds__(512, 2)
void gru_mfma(const float* __restrict__ x, const short8* __restrict__ xw,
              const float* __restrict__ mask,
              const float* __restrict__ w_ih, const float* __restrict__ w_hh,
              const float* __restrict__ b_ih, const float* __restrict__ b_hh,
              const float* __restrict__ Wo, const float* __restrict__ bo,
              float* __restrict__ out)
{
    __shared__ short hbuf[2][16][136];    // h(t) bf16, A-frag layout (8.7 KB)
    __shared__ float exch[4][TH][12];     // acc exchange [acc][col][row+pad] (24 KB)
    __shared__ float mlds[TT][NR];        // mask slice (32 KB)

    const int tid  = threadIdx.x;
    const int w    = tid >> 6;
    const int lane = tid & 63;
    const int c    = lane & 15;
    const int quad = lane >> 4;
    const int Bb   = blockIdx.x * NR;

    // ---- one-time staging ----
    for (int i = tid; i < TT * NR; i += 512) {
        int b = i >> 10, t = i & (TT - 1);
        mlds[t][b] = mask[(size_t)(Bb + b) * TT + t];
    }
    for (int i = tid; i < 2 * 16 * 136; i += 512) (&hbuf[0][0][0])[i] = 0;

    const int jr = 16 * w + c;            // phase-A gate column of this lane

    // ---- weights -> bf16 B-fragments in registers ----
    short8 whh[3][4], wih[3][2], wof[4];
    {
        const int gg[3] = {jr, TH + jr, 2 * TH + jr};
        #pragma unroll
        for (int g = 0; g < 3; ++g) {
            #pragma unroll
            for (int kt = 0; kt < 4; ++kt) {
                const float* p = w_hh + (size_t)gg[g] * TH + 32 * kt + 8 * quad;
                short8 f;
                #pragma unroll
                for (int j = 0; j < 8; ++j) f[j] = bfb(p[j]);
                whh[g][kt] = f;
            }
            #pragma unroll
            for (int kt = 0; kt < 2; ++kt) {
                const float* p = w_ih + (size_t)gg[g] * TD + 32 * kt + 8 * quad;
                short8 f;
                #pragma unroll
                for (int j = 0; j < 8; ++j) f[j] = bfb(p[j]);
                wih[g][kt] = f;
            }
        }
        #pragma unroll
        for (int kt = 0; kt < 4; ++kt) {
            short8 f = {0,0,0,0,0,0,0,0};
            if (c < 2) {
                const float* p = Wo + (size_t)c * TH + 32 * kt + 8 * quad;
                #pragma unroll
                for (int j = 0; j < 8; ++j) f[j] = bfb(p[j]);
            }
            wof[kt] = f;
        }
    }

    // ---- phase-B per-thread constants ----
    const int jj = tid >> 2;              // hidden col 0..127
    const int rr = tid & 3;               // rows rr and rr+4
    const float crK = -LOG2E * (b_ih[jj] + b_hh[jj]);
    const float czK = -LOG2E * (b_ih[TH + jj] + b_hh[TH + jj]);
    const float bin = b_ih[2 * TH + jj];
    const float bhn = b_hh[2 * TH + jj];
    const float boc = (c < 2) ? bo[c] : 0.0f;

    const short8 z8 = {0,0,0,0,0,0,0,0};

    // x access bases
    const short8* xwp  = xw + (size_t)blockIdx.x * (TT * 64) + (c * 4 + quad);
    const float*  xrow = x + (size_t)(Bb + (c < 8 ? c : 0)) * TT * TD + 8 * quad;

    short8 xf0[2], xf1[2];
    if (USE_WS) {
        xf0[0] = (c < 8) ? xwp[0]  : z8;
        xf0[1] = (c < 8) ? xwp[32] : z8;
    } else {
        #pragma unroll
        for (int kt = 0; kt < 2; ++kt) {
            f32x4 a = *(const f32x4*)(xrow + 32 * kt);
            f32x4 b = *(const f32x4*)(xrow + 32 * kt + 4);
            short8 f = z8;
            if (c < 8) {
                #pragma unroll
                for (int j = 0; j < 4; ++j) { f[j] = bfb(a[j]); f[4 + j] = bfb(b[j]); }
            }
            xf0[kt] = f;
        }
    }

    float hold0 = 0.0f, hold1 = 0.0f;     // fp32 h for (rr, jj), (rr+4, jj)

#define STEP(T, XC, XN)                                                         \
  {                                                                             \
    const int t = (T);                                                          \
    BAR();                                                                      \
    const int rb = t & 1, wb = rb ^ 1;                                          \
    short8 ha[4];                                                               \
    _Pragma("unroll")                                                           \
    for (int kt = 0; kt < 4; ++kt)                                              \
        ha[kt] = *(const short8*)(&hbuf[rb][c][32 * kt + 8 * quad]);            \
    const int tn = (t + 1 < TT) ? t + 1 : TT - 1;                               \
    if (USE_WS) {                                                               \
        XN[0] = (c < 8) ? xwp[(size_t)tn * 64]      : z8;                       \
        XN[1] = (c < 8) ? xwp[(size_t)tn * 64 + 32] : z8;                       \
    } else {                                                                    \
        const float* p = xrow + (size_t)tn * TD;                                \
        f32x4 a0 = *(const f32x4*)(p),      b0 = *(const f32x4*)(p + 4);        \
        f32x4 a1 = *(const f32x4*)(p + 32), b1 = *(const f32x4*)(p + 36);       \
        short8 f0 = z8, f1 = z8;                                                \
        if (c < 8) {                                                            \
            _Pragma("unroll")                                                   \
            for (int j = 0; j < 4; ++j) { f0[j] = bfb(a0[j]); f0[4+j] = bfb(b0[j]); \
                                          f1[j] = bfb(a1[j]); f1[4+j] = bfb(b1[j]); } \
        }                                                                       \
        XN[0] = f0; XN[1] = f1;                                                 \
    }                                                                           \
    f32x4 ar = {0.f,0.f,0.f,0.f}, az = {0.f,0.f,0.f,0.f};                       \
    f32x4 anh = {0.f,0.f,0.f,0.f}, anx = {0.f,0.f,0.f,0.f};                     \
    _Pragma("unroll")                                                           \
    for (int kt = 0; kt < 4; ++kt) {                                            \
        ar  = __builtin_amdgcn_mfma_f32_16x16x32_bf16(ha[kt], whh[0][kt], ar , 0,0,0); \
        az  = __builtin_amdgcn_mfma_f32_16x16x32_bf16(ha[kt], whh[1][kt], az , 0,0,0); \
        anh = __builtin_amdgcn_mfma_f32_16x16x32_bf16(ha[kt], whh[2][kt], anh, 0,0,0); \
    }                                                                           \
    _Pragma("unroll")                                                           \
    for (int kt = 0; kt < 2; ++kt) {                                            \
        ar  = __builtin_amdgcn_mfma_f32_16x16x32_bf16(XC[kt], wih[0][kt], ar , 0,0,0); \
        az  = __builtin_amdgcn_mfma_f32_16x16x32_bf16(XC[kt], wih[1][kt], az , 0,0,0); \
        anx = __builtin_amdgcn_mfma_f32_16x16x32_bf16(XC[kt], wih[2][kt], anx, 0,0,0); \
    }                                                                           \
    /* logits for t-1 (rotating wave; every wave holds wof + identical ha) */   \
    if (t > 0 && w == ((t - 1) & 7)) {                                          \
        f32x4 lacc = {0.f, 0.f, 0.f, 0.f};                                      \
        _Pragma("unroll")                                                       \
        for (int kt = 0; kt < 4; ++kt)                                          \
            lacc = __builtin_amdgcn_mfma_f32_16x16x32_bf16(ha[kt], wof[kt], lacc, 0,0,0); \
        if (c < 2 && quad < 2) {                                                \
            _Pragma("unroll")                                                   \
            for (int i = 0; i < 4; ++i)                                         \
                out[((size_t)(Bb + 4 * quad + i) * TT + (t - 1)) * 2 + c] = lacc[i] + boc; \
        }                                                                       \
    }                                                                           \
    if (quad < 2) {   /* real C/D rows 0..7 -> exchange */                      \
        *(f32x4*)(&exch[0][jr][4 * quad]) = ar;                                 \
        *(f32x4*)(&exch[1][jr][4 * quad]) = az;                                 \
        *(f32x4*)(&exch[2][jr][4 * quad]) = anh;                                \
        *(f32x4*)(&exch[3][jr][4 * quad]) = anx;                                \
    }                                                                           \
    BAR();                                                                      \
    {                                                                           \
        float a0 = exch[0][jj][rr],     z0 = exch[1][jj][rr];                   \
        float nh0 = exch[2][jj][rr],    nx0 = exch[3][jj][rr];                  \
        float a1 = exch[0][jj][rr + 4], z1 = exch[1][jj][rr + 4];               \
        float nh1 = exch[2][jj][rr + 4], nx1 = exch[3][jj][rr + 4];             \
        float m0 = mlds[t][rr], m1 = mlds[t][rr + 4];                           \
        hold0 = gate_update(a0, z0, nx0, nh0, crK, czK, bin, bhn, m0, hold0);   \
        hold1 = gate_update(a1, z1, nx1, nh1, crK, czK, bin, bhn, m1, hold1);   \
        hbuf[wb][rr][jj]     = bfb(hold0);                                      \
        hbuf[wb][rr + 4][jj] = bfb(hold1);                                      \
    }                                                                           \
  }

    for (int t2 = 0; t2 < TT; t2 += 2) {
        STEP(t2,     xf0, xf1);
        STEP(t2 + 1, xf1, xf0);
    }
#undef STEP

    // flush logits for t = TT-1 (h(TT-1) sits in hbuf[0])
    BAR();
    if (w == 0) {
        short8 ha[4];
        #pragma unroll
        for (int kt = 0; kt < 4; ++kt)
            ha[kt] = *(const short8*)(&hbuf[0][c][32 * kt + 8 * quad]);
        f32x4 lacc = {0.f, 0.f, 0.f, 0.f};
        #pragma unroll
        for (int kt = 0; kt < 4; ++kt)
            lacc = __builtin_amdgcn_mfma_f32_16x16x32_bf16(ha[kt], wof[kt], lacc, 0, 0, 0);
        if (c < 2 && quad < 2) {
            #pragma unroll
            for (int i = 0; i < 4; ++i)
                out[((size_t)(Bb + 4 * quad + i) * TT + (TT - 1)) * 2 + c] = lacc[i] + boc;
        }
    }
}

extern "C" void kernel_launch(void* const* d_in, const int* in_sizes, int n_in,
                              void* d_out, int out_size, void* d_ws, size_t ws_size,
                              hipStream_t stream) {
    const float* x    = (const float*)d_in[0];
    const float* mask = (const float*)d_in[1];
    const float* w_ih = (const float*)d_in[2];
    const float* w_hh = (const float*)d_in[3];
    const float* b_ih = (const float*)d_in[4];
    const float* b_hh = (const float*)d_in[5];
    const float* Wo   = (const float*)d_in[6];
    const float* bo   = (const float*)d_in[7];
    float* out = (float*)d_out;
    (void)in_sizes; (void)n_in; (void)out_size;

    const size_t nfrag = (size_t)(TB / NR) * TT * 2 * 32;       // 4.19M short8
    const size_t need  = nfrag * sizeof(short8);                // 67.1 MB
    if (ws_size >= need) {
        short8* xw = (short8*)d_ws;
        xswz<<<(int)(nfrag / 256), 256, 0, stream>>>(x, xw);
        gru_mfma<true><<<TB / NR, 512, 0, stream>>>(x, xw, mask, w_ih, w_hh,
                                                    b_ih, b_hh, Wo, bo, out);
    } else {
        gru_mfma<false><<<TB / NR, 512, 0, stream>>>(x, (const short8*)nullptr, mask,
                                                     w_ih, w_hh, b_ih, b_hh, Wo, bo, out);
    }
}

// Round 5
// 965.428 us; speedup vs baseline: 2.8484x; 1.1157x over previous
//
#include <hip/hip_runtime.h>

#define TB 512   // batch
#define TT 1024  // time
#define TD 64    // input dim
#define TH 128   // hidden
#define NR 4     // batch rows per block -> 128 blocks / 128 CUs

typedef __attribute__((ext_vector_type(8))) short short8;  // 8 bf16 (4 VGPRs)
typedef __attribute__((ext_vector_type(4))) float f32x4;   // MFMA C/D

#define LOG2E 1.44269504f

// fp32 -> bf16 bits, round-to-nearest-even
__device__ __forceinline__ short bfb(float f) {
    unsigned u = __builtin_bit_cast(unsigned, f);
    u = (u + 0x7FFFu + ((u >> 16) & 1u)) >> 16;
    return (short)u;
}

// Barrier with LDS-only drain: global loads/stores stay in flight across it.
#define BAR() asm volatile("s_waitcnt lgkmcnt(0)\n\ts_barrier" ::: "memory")
// compiler-only ordering fence (intra-wave DS write -> read; HW DS pipe is
// in-order per wave, we only need to stop compiler reordering)
#define WAVE_FENCE() asm volatile("" ::: "memory")

// ---------------- phase 1: x -> bf16 A-fragment order (compact, 4 rows) -----
// ws layout (short8 units): [blk 0..127][t][kt 0..1][e 0..15], e = c*4 + quad
// holds x[blk*4 + c][t][32*kt + 8*quad + j], j=0..7
__global__ __launch_bounds__(256)
void xswz(const float* __restrict__ x, short8* __restrict__ ws) {
    int gid = blockIdx.x * 256 + threadIdx.x;   // 128*1024*2*16 = 4.19M
    int e   = gid & 15;
    int kt  = (gid >> 4) & 1;
    int t   = (gid >> 5) & (TT - 1);
    int blk = gid >> 15;
    int c = e >> 2, quad = e & 3;
    const float* p = x + ((size_t)(blk * NR + c) * TT + t) * TD + 32 * kt + 8 * quad;
    f32x4 a = *(const f32x4*)p;
    f32x4 b = *(const f32x4*)(p + 4);
    short8 f;
    #pragma unroll
    for (int j = 0; j < 4; ++j) { f[j] = bfb(a[j]); f[4 + j] = bfb(b[j]); }
    ws[gid] = f;
}

// ---------------- phase 2: the scan -----------------------------------------
// 128 blocks x 512 threads. Block owns 4 batch rows (MFMA rows 4..15 zero).
// Wave w owns gate cols {16w+c, +128, +256}. After MFMA, quad-0 lanes hold all
// 4 real C/D rows; an INTRA-WAVE LDS exchange (no barrier: same-wave DS ops
// are pipe-ordered) hands each lane exactly one (row=quad, col=16w+c) triple.
template <bool USE_WS>
__global__ __launch_bounds__(512, 2)
void gru_mfma(const float* __restrict__ x, const short8* __restrict__ xw,
              const float* __restrict__ mask,
              const float* __restrict__ w_ih, const float* __restrict__ w_hh,
              const float* __restrict__ b_ih, const float* __restrict__ b_hh,
              const float* __restrict__ Wo, const float* __restrict__ bo,
              float* __restrict__ out)
{
    __shared__ short hbuf[2][16][136];    // h(t) bf16 A-frag; rows 4..15 stay 0
    __shared__ float exws[8][4][16][4];   // per-wave acc exchange (8 KB)
    __shared__ float mlds[TT][NR];        // mask slice (16 KB)

    const int tid  = threadIdx.x;
    const int w    = tid >> 6;
    const int lane = tid & 63;
    const int c    = lane & 15;
    const int quad = lane >> 4;
    const int Bb   = blockIdx.x * NR;

    // ---- one-time staging ----
    for (int i = tid; i < TT * NR; i += 512) {
        int t = i >> 2, b = i & 3;
        mlds[t][b] = mask[(size_t)(Bb + b) * TT + t];
    }
    for (int i = tid; i < 2 * 16 * 136; i += 512) (&hbuf[0][0][0])[i] = 0;

    const int jj = 16 * w + c;            // gate column this lane owns

    // ---- weights -> bf16 B-fragments in registers ----
    short8 whh[3][4], wih[3][2], wof[4];
    {
        const int gg[3] = {jj, TH + jj, 2 * TH + jj};
        #pragma unroll
        for (int g = 0; g < 3; ++g) {
            #pragma unroll
            for (int kt = 0; kt < 4; ++kt) {
                const float* p = w_hh + (size_t)gg[g] * TH + 32 * kt + 8 * quad;
                short8 f;
                #pragma unroll
                for (int j = 0; j < 8; ++j) f[j] = bfb(p[j]);
                whh[g][kt] = f;
            }
            #pragma unroll
            for (int kt = 0; kt < 2; ++kt) {
                const float* p = w_ih + (size_t)gg[g] * TD + 32 * kt + 8 * quad;
                short8 f;
                #pragma unroll
                for (int j = 0; j < 8; ++j) f[j] = bfb(p[j]);
                wih[g][kt] = f;
            }
        }
        #pragma unroll
        for (int kt = 0; kt < 4; ++kt) {
            short8 f = {0,0,0,0,0,0,0,0};
            if (c < 2) {
                const float* p = Wo + (size_t)c * TH + 32 * kt + 8 * quad;
                #pragma unroll
                for (int j = 0; j < 8; ++j) f[j] = bfb(p[j]);
            }
            wof[kt] = f;
        }
    }

    // epilogue constants for col jj (same for all 4 rows)
    const float crK = -LOG2E * (b_ih[jj] + b_hh[jj]);
    const float czK = -LOG2E * (b_ih[TH + jj] + b_hh[TH + jj]);
    const float bin = b_ih[2 * TH + jj];
    const float bhn = b_hh[2 * TH + jj];
    const float boc = (c < 2) ? bo[c] : 0.0f;

    const short8 z8 = {0,0,0,0,0,0,0,0};

    // x access bases
    const short8* xwp  = xw + (size_t)blockIdx.x * (TT * 32) + (c * 4 + quad);
    const float*  xrow = x + (size_t)(Bb + (c < 4 ? c : 0)) * TT * TD + 8 * quad;

    short8 xf0[2], xf1[2];
    if (USE_WS) {
        xf0[0] = (c < 4) ? xwp[0]  : z8;
        xf0[1] = (c < 4) ? xwp[16] : z8;
    } else {
        #pragma unroll
        for (int kt = 0; kt < 2; ++kt) {
            f32x4 a = *(const f32x4*)(xrow + 32 * kt);
            f32x4 b = *(const f32x4*)(xrow + 32 * kt + 4);
            short8 f = z8;
            if (c < 4) {
                #pragma unroll
                for (int j = 0; j < 4; ++j) { f[j] = bfb(a[j]); f[4 + j] = bfb(b[j]); }
            }
            xf0[kt] = f;
        }
    }

    float hold = 0.0f;                    // fp32 h for (row=quad, col=jj)

#define STEP(T, XC, XN)                                                         \
  {                                                                             \
    const int t = (T);                                                          \
    BAR();                                                                      \
    const int rb = t & 1, wb = rb ^ 1;                                          \
    short8 ha[4];                                                               \
    _Pragma("unroll")                                                           \
    for (int kt = 0; kt < 4; ++kt)                                              \
        ha[kt] = *(const short8*)(&hbuf[rb][c][32 * kt + 8 * quad]);            \
    const int tn = (t + 1 < TT) ? t + 1 : TT - 1;                               \
    f32x4 nxa0, nxb0, nxa1, nxb1;                                               \
    if (USE_WS) {                                                               \
        XN[0] = (c < 4) ? xwp[(size_t)tn * 32]      : z8;                       \
        XN[1] = (c < 4) ? xwp[(size_t)tn * 32 + 16] : z8;                       \
    } else {                                                                    \
        const float* p = xrow + (size_t)tn * TD;                                \
        nxa0 = *(const f32x4*)(p);      nxb0 = *(const f32x4*)(p + 4);          \
        nxa1 = *(const f32x4*)(p + 32); nxb1 = *(const f32x4*)(p + 36);         \
    }                                                                           \
    /* x-MFMAs first (operands pre-barrier-ready; overlaps ha ds_read) */       \
    f32x4 ar = {0.f,0.f,0.f,0.f}, az = {0.f,0.f,0.f,0.f};                       \
    f32x4 anh = {0.f,0.f,0.f,0.f}, anx = {0.f,0.f,0.f,0.f};                     \
    _Pragma("unroll")                                                           \
    for (int kt = 0; kt < 2; ++kt) {                                            \
        ar  = __builtin_amdgcn_mfma_f32_16x16x32_bf16(XC[kt], wih[0][kt], ar , 0,0,0); \
        az  = __builtin_amdgcn_mfma_f32_16x16x32_bf16(XC[kt], wih[1][kt], az , 0,0,0); \
        anx = __builtin_amdgcn_mfma_f32_16x16x32_bf16(XC[kt], wih[2][kt], anx, 0,0,0); \
    }                                                                           \
    _Pragma("unroll")                                                           \
    for (int kt = 0; kt < 4; ++kt) {                                            \
        ar  = __builtin_amdgcn_mfma_f32_16x16x32_bf16(ha[kt], whh[0][kt], ar , 0,0,0); \
        az  = __builtin_amdgcn_mfma_f32_16x16x32_bf16(ha[kt], whh[1][kt], az , 0,0,0); \
        anh = __builtin_amdgcn_mfma_f32_16x16x32_bf16(ha[kt], whh[2][kt], anh, 0,0,0); \
    }                                                                           \
    /* logits for t-1 (rotating wave) */                                        \
    if (t > 0 && w == ((t - 1) & 7)) {                                          \
        f32x4 lacc = {0.f, 0.f, 0.f, 0.f};                                      \
        _Pragma("unroll")                                                       \
        for (int kt = 0; kt < 4; ++kt)                                          \
            lacc = __builtin_amdgcn_mfma_f32_16x16x32_bf16(ha[kt], wof[kt], lacc, 0,0,0); \
        if (c < 2 && quad == 0) {                                               \
            _Pragma("unroll")                                                   \
            for (int i = 0; i < 4; ++i)                                         \
                out[((size_t)(Bb + i) * TT + (t - 1)) * 2 + c] = lacc[i] + boc; \
        }                                                                       \
    }                                                                           \
    /* intra-wave exchange: quad0 lanes hold rows 0..3; same-wave DS ops are */ \
    /* pipe-ordered, so no barrier between write and read */                    \
    if (quad == 0) {                                                            \
        *(f32x4*)(&exws[w][0][c][0]) = ar;                                      \
        *(f32x4*)(&exws[w][1][c][0]) = az;                                      \
        *(f32x4*)(&exws[w][2][c][0]) = anh;                                     \
        *(f32x4*)(&exws[w][3][c][0]) = anx;                                     \
    }                                                                           \
    WAVE_FENCE();                                                               \
    {                                                                           \
        float arS  = exws[w][0][c][quad];                                       \
        float azS  = exws[w][1][c][quad];                                       \
        float anhS = exws[w][2][c][quad];                                       \
        float anxS = exws[w][3][c][quad];                                       \
        float m    = mlds[t][quad];                                             \
        float er = __builtin_amdgcn_exp2f(__builtin_fmaf(arS, -LOG2E, crK));    \
        float r  = __builtin_amdgcn_rcpf(1.0f + er);                            \
        float ez = __builtin_amdgcn_exp2f(__builtin_fmaf(azS, -LOG2E, czK));    \
        float z  = __builtin_amdgcn_rcpf(1.0f + ez);                            \
        float p  = (anxS + bin) + r * (anhS + bhn);                             \
        float e2 = __builtin_amdgcn_exp2f(p * (2.0f * LOG2E));                  \
        float n  = __builtin_fmaf(-2.0f, __builtin_amdgcn_rcpf(1.0f + e2), 1.0f); \
        float hn = n + z * (hold - n);                                          \
        hold = hold + m * (hn - hold);                                          \
        hbuf[wb][quad][jj] = bfb(hold);                                         \
    }                                                                           \
    if (!USE_WS) {                                                              \
        short8 f0 = z8, f1 = z8;                                                \
        if (c < 4) {                                                            \
            _Pragma("unroll")                                                   \
            for (int j = 0; j < 4; ++j) { f0[j] = bfb(nxa0[j]); f0[4+j] = bfb(nxb0[j]); \
                                          f1[j] = bfb(nxa1[j]); f1[4+j] = bfb(nxb1[j]); } \
        }                                                                       \
        XN[0] = f0; XN[1] = f1;                                                 \
    }                                                                           \
  }

    for (int t2 = 0; t2 < TT; t2 += 2) {
        STEP(t2,     xf0, xf1);
        STEP(t2 + 1, xf1, xf0);
    }
#undef STEP

    // flush logits for t = TT-1 (h(TT-1) sits in hbuf[0])
    BAR();
    if (w == 7) {
        short8 ha[4];
        #pragma unroll
        for (int kt = 0; kt < 4; ++kt)
            ha[kt] = *(const short8*)(&hbuf[0][c][32 * kt + 8 * quad]);
        f32x4 lacc = {0.f, 0.f, 0.f, 0.f};
        #pragma unroll
        for (int kt = 0; kt < 4; ++kt)
            lacc = __builtin_amdgcn_mfma_f32_16x16x32_bf16(ha[kt], wof[kt], lacc, 0, 0, 0);
        if (c < 2 && quad == 0) {
            #pragma unroll
            for (int i = 0; i < 4; ++i)
                out[((size_t)(Bb + i) * TT + (TT - 1)) * 2 + c] = lacc[i] + boc;
        }
    }
}

extern "C" void kernel_launch(void* const* d_in, const int* in_sizes, int n_in,
                              void* d_out, int out_size, void* d_ws, size_t ws_size,
                              hipStream_t stream) {
    const float* x    = (const float*)d_in[0];
    const float* mask = (const float*)d_in[1];
    const float* w_ih = (const float*)d_in[2];
    const float* w_hh = (const float*)d_in[3];
    const float* b_ih = (const float*)d_in[4];
    const float* b_hh = (const float*)d_in[5];
    const float* Wo   = (const float*)d_in[6];
    const float* bo   = (const float*)d_in[7];
    float* out = (float*)d_out;
    (void)in_sizes; (void)n_in; (void)out_size;

    const size_t nfrag = (size_t)(TB / NR) * TT * 2 * 16;       // 4.19M short8
    const size_t need  = nfrag * sizeof(short8);                // 67.1 MB
    if (ws_size >= need) {
        short8* xw = (short8*)d_ws;
        xswz<<<(int)(nfrag / 256), 256, 0, stream>>>(x, xw);
        gru_mfma<true><<<TB / NR, 512, 0, stream>>>(x, xw, mask, w_ih, w_hh,
                                                    b_ih, b_hh, Wo, bo, out);
    } else {
        gru_mfma<false><<<TB / NR, 512, 0, stream>>>(x, (const short8*)nullptr, mask,
                                                     w_ih, w_hh, b_ih, b_hh, Wo, bo, out);
    }
}